// Round 1
// baseline (167.534 us; speedup 1.0000x reference)
//
#include <hip/hip_runtime.h>
#include <math.h>

// Problem constants (match reference)
#define NB 16
#define NC 512
#define NL 8192
#define KW 7

// ---------------------------------------------------------------------------
// Kernel 1: channel-wise max + mean pooling.
// One thread per (b, l). Loop over C with stride-L loads (coalesced across
// lanes since consecutive threads have consecutive l).
// Writes feats into workspace: plane layout [b][0][l] = max, [b][1][l] = mean.
// ---------------------------------------------------------------------------
__global__ __launch_bounds__(256) void sam1d_pool(
    const float* __restrict__ x, float* __restrict__ feats) {
    const int gid = blockIdx.x * 256 + threadIdx.x;   // over NB*NL
    const int b = gid / NL;
    const int l = gid - b * NL;

    const float* p = x + (size_t)b * NC * NL + l;
    float mx = -INFINITY;
    float sm = 0.0f;
#pragma unroll 8
    for (int c = 0; c < NC; ++c) {
        float v = p[(size_t)c * NL];
        mx = fmaxf(mx, v);
        sm += v;
    }
    float* f = feats + (size_t)b * 2 * NL;
    f[l]      = mx;
    f[NL + l] = sm * (1.0f / (float)NC);
}

// ---------------------------------------------------------------------------
// Kernel 2: 7-tap conv over feats (zero-padded) + sigmoid, then broadcast
// multiply over all C channels of x.
// One thread per (b, l); conv reads are L1/L2-resident (feats = 1 MiB).
// ---------------------------------------------------------------------------
__global__ __launch_bounds__(256) void sam1d_apply(
    const float* __restrict__ x, const float* __restrict__ feats,
    const float* __restrict__ w, float* __restrict__ out) {
    const int gid = blockIdx.x * 256 + threadIdx.x;   // over NB*NL
    const int b = gid / NL;
    const int l = gid - b * NL;

    const float* fm = feats + (size_t)b * 2 * NL;  // max plane
    const float* fa = fm + NL;                     // avg plane

    float logit = 0.0f;
#pragma unroll
    for (int k = 0; k < KW; ++k) {
        int ll = l + k - (KW / 2);
        if (ll >= 0 && ll < NL) {
            logit = fmaf(fm[ll], w[k], logit);
            logit = fmaf(fa[ll], w[KW + k], logit);
        }
    }
    const float attn = 1.0f / (1.0f + expf(-logit));

    const float* px = x + (size_t)b * NC * NL + l;
    float* po = out + (size_t)b * NC * NL + l;
#pragma unroll 8
    for (int c = 0; c < NC; ++c) {
        po[(size_t)c * NL] = attn * px[(size_t)c * NL];
    }
}

extern "C" void kernel_launch(void* const* d_in, const int* in_sizes, int n_in,
                              void* d_out, int out_size, void* d_ws, size_t ws_size,
                              hipStream_t stream) {
    const float* x = (const float*)d_in[0];
    // d_in[1] = mask — intentionally unused (reference discards masked_fill).
    const float* w = (const float*)d_in[2];   // (1,2,7) flat: [0..6]=max taps, [7..13]=avg taps
    float* out = (float*)d_out;
    float* feats = (float*)d_ws;              // NB*2*NL floats = 1 MiB

    const int total = NB * NL;                // 131072
    const int blocks = total / 256;           // 512

    sam1d_pool<<<blocks, 256, 0, stream>>>(x, feats);
    sam1d_apply<<<blocks, 256, 0, stream>>>(x, feats, w, out);
}

// Round 2
// 164.209 us; speedup vs baseline: 1.0203x; 1.0203x over previous
//
#include <hip/hip_runtime.h>
#include <math.h>

// Problem constants (match reference)
#define NB 16
#define NC 512
#define NL 8192
#define KW 7

// Fused single-pass tiling
#define TILE 64                        // columns loaded per block (incl. halo)
#define HALO (KW / 2)                  // 3
#define TIN  (TILE - 2 * HALO)         // 58 interior (written) columns
#define NTILES ((NL + TIN - 1) / TIN)  // 142
#define CG  16                         // channel groups (one per pair-of-waves)
#define CPT (NC / CG)                  // 32 channels per thread, held in VGPRs

// ---------------------------------------------------------------------------
// One block = (batch b, column tile t). 1024 threads = 64 columns x 16
// channel-groups. Each thread loads its 32-channel slice of one column into
// registers (read x ONCE), partial max/sum -> LDS -> cross-group reduce ->
// pooled max/avg per column -> 7-tap conv + sigmoid from LDS -> multiply the
// register-held x slice and write out. Halo columns (3 each side) are loaded
// redundantly by neighboring blocks; interiors are disjoint and cover [0,L).
// ---------------------------------------------------------------------------
__global__ __launch_bounds__(1024) void sam1d_fused(
    const float* __restrict__ x, const float* __restrict__ w,
    float* __restrict__ out) {
    __shared__ float lds_mx[CG * TILE];
    __shared__ float lds_sm[CG * TILE];
    __shared__ float pool_mx[TILE];
    __shared__ float pool_av[TILE];

    const int tid  = threadIdx.x;
    const int lcol = tid & (TILE - 1);
    const int cg   = tid >> 6;                 // 0..15
    const int blk  = blockIdx.x;
    const int b    = blk / NTILES;
    const int t    = blk - b * NTILES;
    const int l    = t * TIN - HALO + lcol;    // global column
    const bool lvalid = (l >= 0) && (l < NL);

    const float* px = x + (size_t)b * NC * NL + (size_t)(cg * CPT) * NL + l;

    float xv[CPT];
    if (lvalid) {
#pragma unroll
        for (int j = 0; j < CPT; ++j) xv[j] = px[(size_t)j * NL];
    } else {
#pragma unroll
        for (int j = 0; j < CPT; ++j) xv[j] = 0.0f;
    }

    // per-thread partial pooling over 32 channels
    float mx = xv[0], sm = xv[0];
#pragma unroll
    for (int j = 1; j < CPT; ++j) { mx = fmaxf(mx, xv[j]); sm += xv[j]; }
    lds_mx[cg * TILE + lcol] = mx;
    lds_sm[cg * TILE + lcol] = sm;
    __syncthreads();

    // cross-group reduction: 64 threads do max, 64 do sum (conflict-free,
    // stride TILE=64 floats between iterations, consecutive within a wave)
    if (tid < TILE) {
        float m = lds_mx[tid];
#pragma unroll
        for (int g = 1; g < CG; ++g) m = fmaxf(m, lds_mx[g * TILE + tid]);
        const int gl = t * TIN - HALO + tid;
        pool_mx[tid] = (gl >= 0 && gl < NL) ? m : 0.0f;  // conv zero-padding
    } else if (tid < 2 * TILE) {
        const int c = tid - TILE;
        float s = lds_sm[c];
#pragma unroll
        for (int g = 1; g < CG; ++g) s += lds_sm[g * TILE + c];
        const int gl = t * TIN - HALO + c;
        pool_av[c] = (gl >= 0 && gl < NL) ? s * (1.0f / (float)NC) : 0.0f;
    }
    __syncthreads();

    // interior columns: conv (cross-correlation, no flip) + sigmoid + apply
    if (lcol >= HALO && lcol < HALO + TIN && l < NL) {
        float logit = 0.0f;
#pragma unroll
        for (int k = 0; k < KW; ++k) {
            logit = fmaf(pool_mx[lcol - HALO + k], w[k],      logit);
            logit = fmaf(pool_av[lcol - HALO + k], w[KW + k], logit);
        }
        const float attn = 1.0f / (1.0f + expf(-logit));
        float* po = out + (size_t)b * NC * NL + (size_t)(cg * CPT) * NL + l;
#pragma unroll
        for (int j = 0; j < CPT; ++j) po[(size_t)j * NL] = attn * xv[j];
    }
}

extern "C" void kernel_launch(void* const* d_in, const int* in_sizes, int n_in,
                              void* d_out, int out_size, void* d_ws, size_t ws_size,
                              hipStream_t stream) {
    const float* x = (const float*)d_in[0];
    // d_in[1] = mask — intentionally unused (reference discards masked_fill).
    const float* w = (const float*)d_in[2];   // flat (1,2,7): [0..6]=max taps, [7..13]=avg taps
    float* out = (float*)d_out;

    const int blocks = NB * NTILES;  // 16 * 142 = 2272
    sam1d_fused<<<blocks, 1024, 0, stream>>>(x, w, out);
}